// Round 4
// baseline (451.002 us; speedup 1.0000x reference)
//
#include <hip/hip_runtime.h>
#include <hip/hip_bf16.h>
#include <cstddef>
#include <cstdint>

// Problem constants (fixed by the reference)
#define N_TOK 16384     // B*S = 32*512
#define H_    2048
#define FP_   1024
#define SP_   1024
#define C_    2050      // 2 + FP + SP, prob_all row stride

#define BM 128
#define BN 128
#define BK 64
#define KP 72           // padded stride for the FALLBACK fused kernel only

typedef short bf16x8 __attribute__((ext_vector_type(8)));  // 8 bf16 = 4 VGPRs
typedef float f32x4  __attribute__((ext_vector_type(4)));  // 4 fp32 acc

__device__ __forceinline__ unsigned pack_bf2(float a, float b) {
  __hip_bfloat16 x = __float2bfloat16(a);
  __hip_bfloat16 y = __float2bfloat16(b);
  unsigned short ux, uy;
  __builtin_memcpy(&ux, &x, 2);
  __builtin_memcpy(&uy, &y, 2);
  return (unsigned)ux | ((unsigned)uy << 16);
}

__device__ __forceinline__ unsigned short f2bf(float f) {
  __hip_bfloat16 h = __float2bfloat16(f);
  unsigned short u;
  __builtin_memcpy(&u, &h, 2);
  return u;
}

__device__ __forceinline__ float bf2f(unsigned short u) {
  unsigned v = (unsigned)u << 16;
  float f;
  __builtin_memcpy(&f, &v, 4);
  return f;
}

// ---------------------------------------------------------------------------
// FAST PATH kernel 1: fp32 -> bf16 pre-convert of X (rows 0..16383) and
// W_hcw|W_roo (rows 16384..18431) into d_ws, fusing the end-head dot
// (fp32-exact) into the X pass. One wave per row, 4 rows/block.  (unchanged)
// ---------------------------------------------------------------------------
__global__ __launch_bounds__(256) void convert_kernel(
    const float* __restrict__ X,
    const float* __restrict__ W_hcw, const float* __restrict__ W_roo,
    const float* __restrict__ W_end, const float* __restrict__ b_end,
    unsigned short* __restrict__ Xb, unsigned short* __restrict__ Wb,
    float* __restrict__ mat)
{
  const int wave = threadIdx.x >> 6;
  const int lane = threadIdx.x & 63;
  const int row  = (blockIdx.x << 2) + wave;
  const bool isX = row < N_TOK;
  const float* src;
  unsigned short* dst;
  if (isX) {
    src = X + (size_t)row * H_;
    dst = Xb + (size_t)row * H_;
  } else {
    const int m = row - N_TOK;
    src = (m < FP_) ? (W_hcw + (size_t)m * H_) : (W_roo + (size_t)(m - FP_) * H_);
    dst = Wb + (size_t)m * H_;
  }
  float s = 0.f;
#pragma unroll
  for (int i = 0; i < 8; ++i) {
    const int e = (lane << 2) + (i << 8);      // lane*4 + i*256: coalesced
    float4 v = *(const float4*)(src + e);
    uint2 p;
    p.x = pack_bf2(v.x, v.y);
    p.y = pack_bf2(v.z, v.w);
    *(uint2*)(dst + e) = p;
    if (isX) {                                  // wave-uniform branch
      float4 w = *(const float4*)(W_end + e);
      s += v.x * w.x + v.y * w.y + v.z * w.z + v.w * w.w;
    }
  }
  if (isX) {
#pragma unroll
    for (int o = 32; o; o >>= 1) s += __shfl_xor(s, o);
    if (lane == 0) mat[(size_t)row * C_] = s + b_end[0];
  }
}

// ---------------------------------------------------------------------------
// FAST PATH kernel 2: bf16 MFMA GEMM, async global->LDS staging, XOR-swizzled
// LDS chunk layout (round-4, conflict-free). REVERTED to the proven 128^2
// 2-phase structure (165 us): two rounds of 8-phase/counted-vmcnt schedules
// (r2 coarse, r3 fine) both measured null-to-worse at this problem shape.
// C-tile written as PACKED BF16 logits at float-offset 4 of each mat row.
// ---------------------------------------------------------------------------
__global__ __launch_bounds__(256) void gemm_lds_kernel(
    const unsigned short* __restrict__ Xb, const unsigned short* __restrict__ Wb,
    const float* __restrict__ b_hcw, const float* __restrict__ b_roo,
    float* __restrict__ mat)
{
  __shared__ __align__(16) unsigned short As[BM * BK];   // 16 KB
  __shared__ __align__(16) unsigned short Bs[BN * BK];   // 16 KB

  const int c0 = blockIdx.x * BN;    // class-tile origin; BN divides 1024
  const int n0 = blockIdx.y * BM;    // token-tile origin
  const float* bias = (c0 < FP_) ? (b_hcw + c0) : (b_roo + (c0 - FP_));

  const int t    = threadIdx.x;
  const int wave = t >> 6;
  const int lane = t & 63;
  const int wy   = wave >> 1;
  const int wx   = wave & 1;
  const int quad = lane >> 4;
  const int l16  = lane & 15;

  // staging map: LDS flat byte f = r*4096 + t*16 -> (row = r*32 + t/8,
  // pos = t&7). That slot must hold global chunk pos ^ (row&7).
  const int srow   = t >> 3;                       // 0..31
  const int gchunk = (t & 7) ^ (srow & 7);         // swizzled global chunk
  const unsigned short* gA = Xb + (size_t)(n0 + srow) * H_ + (gchunk << 3);
  const unsigned short* gB = Wb + (size_t)(c0 + srow) * H_ + (gchunk << 3);

  f32x4 acc[4][4];
#pragma unroll
  for (int i = 0; i < 4; ++i)
#pragma unroll
    for (int j = 0; j < 4; ++j)
#pragma unroll
      for (int r = 0; r < 4; ++r) acc[i][j][r] = 0.f;

  for (int k0 = 0; k0 < H_; k0 += BK) {
#pragma unroll
    for (int r = 0; r < 4; ++r) {
      __builtin_amdgcn_global_load_lds(
          (const __attribute__((address_space(1))) unsigned int*)(gA + (size_t)(r * 32) * H_ + k0),
          (__attribute__((address_space(3))) unsigned int*)(&As[(r * 32 + srow) * BK + ((t & 7) << 3)]),
          16, 0, 0);
      __builtin_amdgcn_global_load_lds(
          (const __attribute__((address_space(1))) unsigned int*)(gB + (size_t)(r * 32) * H_ + k0),
          (__attribute__((address_space(3))) unsigned int*)(&Bs[(r * 32 + srow) * BK + ((t & 7) << 3)]),
          16, 0, 0);
    }
    __syncthreads();   // drains vmcnt before barrier (compiler-enforced)

#pragma unroll
    for (int kk = 0; kk < 2; ++kk) {
      bf16x8 af[4], bfr[4];
      const int sw = l16 & 7;                      // row&7 for both A and B rows
#pragma unroll
      for (int i = 0; i < 4; ++i) {
        const int pos = ((kk << 2) + quad) ^ sw;
        af[i] = *(const bf16x8*)&As[(wy * 64 + i * 16 + l16) * BK + (pos << 3)];
      }
#pragma unroll
      for (int j = 0; j < 4; ++j) {
        const int pos = ((kk << 2) + quad) ^ sw;
        bfr[j] = *(const bf16x8*)&Bs[(wx * 64 + j * 16 + l16) * BK + (pos << 3)];
      }
#pragma unroll
      for (int i = 0; i < 4; ++i)
#pragma unroll
        for (int j = 0; j < 4; ++j)
          acc[i][j] = __builtin_amdgcn_mfma_f32_16x16x32_bf16(af[i], bfr[j], acc[i][j], 0, 0, 0);
    }
    __syncthreads();
  }

  // C/D layout: col=lane&15, row=quad*4+reg (m89-verified). Store bf16.
  float bj[4];
#pragma unroll
  for (int j = 0; j < 4; ++j) bj[j] = bias[wx * 64 + j * 16 + l16];
#pragma unroll
  for (int i = 0; i < 4; ++i) {
#pragma unroll
    for (int r = 0; r < 4; ++r) {
      const int row = n0 + wy * 64 + i * 16 + quad * 4 + r;
      unsigned short* dst =
          (unsigned short*)(mat + (size_t)row * C_ + 4) + c0 + wx * 64 + l16;
#pragma unroll
      for (int j = 0; j < 4; ++j) dst[j * 16] = f2bf(acc[i][j][r] + bj[j]);
    }
  }
}

// ---------------------------------------------------------------------------
// FALLBACK kernels (used only if ws_size is too small). Same bf16-logit
// output convention as the fast path so one epilogue serves both.
// ---------------------------------------------------------------------------
__global__ __launch_bounds__(256) void end_head_kernel(
    const float* __restrict__ X, const float* __restrict__ W_end,
    const float* __restrict__ b_end, float* __restrict__ mat)
{
  const int wave = threadIdx.x >> 6;
  const int lane = threadIdx.x & 63;
  const int n = (blockIdx.x << 2) + wave;
  const float* x = X + (size_t)n * H_;
  float s = 0.f;
#pragma unroll
  for (int i = 0; i < 8; ++i) {
    const int e = (lane + (i << 6)) << 2;
    float4 xv = *(const float4*)(x + e);
    float4 wv = *(const float4*)(W_end + e);
    s += xv.x * wv.x + xv.y * wv.y + xv.z * wv.z + xv.w * wv.w;
  }
#pragma unroll
  for (int o = 32; o; o >>= 1) s += __shfl_xor(s, o);
  if (lane == 0) mat[(size_t)n * C_] = s + b_end[0];
}

__global__ __launch_bounds__(256) void logits_gemm_fused(
    const float* __restrict__ X,
    const float* __restrict__ W_hcw, const float* __restrict__ W_roo,
    const float* __restrict__ b_hcw, const float* __restrict__ b_roo,
    float* __restrict__ mat)
{
  __shared__ __align__(16) unsigned short As[BM * KP];
  __shared__ __align__(16) unsigned short Bs[BN * KP];

  const int c0 = blockIdx.x * BN;
  const int n0 = blockIdx.y * BM;
  const float* Wbase = (c0 < FP_) ? (W_hcw + (size_t)c0 * H_)
                                  : (W_roo + (size_t)(c0 - FP_) * H_);
  const float* bias  = (c0 < FP_) ? (b_hcw + c0) : (b_roo + (c0 - FP_));

  const int t    = threadIdx.x;
  const int wave = t >> 6;
  const int lane = t & 63;
  const int wy   = wave >> 1;
  const int wx   = wave & 1;
  const int quad = lane >> 4;
  const int l16  = lane & 15;
  const int tq = t & 3;
  const int tr = t >> 2;

  f32x4 acc[4][4];
#pragma unroll
  for (int i = 0; i < 4; ++i)
#pragma unroll
    for (int j = 0; j < 4; ++j)
#pragma unroll
      for (int r = 0; r < 4; ++r) acc[i][j][r] = 0.f;

  for (int k0 = 0; k0 < H_; k0 += BK) {
#pragma unroll
    for (int p = 0; p < 2; ++p) {
      const int row = tr + (p << 6);
      const float4* xs = (const float4*)(X + (size_t)(n0 + row) * H_ + k0 + (tq << 4));
      const float4* ws = (const float4*)(Wbase + (size_t)row * H_ + k0 + (tq << 4));
      float4 x0 = xs[0], x1 = xs[1], x2 = xs[2], x3 = xs[3];
      float4 w0 = ws[0], w1 = ws[1], w2 = ws[2], w3 = ws[3];
      uint4 ua0 = {pack_bf2(x0.x, x0.y), pack_bf2(x0.z, x0.w),
                   pack_bf2(x1.x, x1.y), pack_bf2(x1.z, x1.w)};
      uint4 ua1 = {pack_bf2(x2.x, x2.y), pack_bf2(x2.z, x2.w),
                   pack_bf2(x3.x, x3.y), pack_bf2(x3.z, x3.w)};
      uint4 ub0 = {pack_bf2(w0.x, w0.y), pack_bf2(w0.z, w0.w),
                   pack_bf2(w1.x, w1.y), pack_bf2(w1.z, w1.w)};
      uint4 ub1 = {pack_bf2(w2.x, w2.y), pack_bf2(w2.z, w2.w),
                   pack_bf2(w3.x, w3.y), pack_bf2(w3.z, w3.w)};
      *(uint4*)&As[row * KP + (tq << 4)]     = ua0;
      *(uint4*)&As[row * KP + (tq << 4) + 8] = ua1;
      *(uint4*)&Bs[row * KP + (tq << 4)]     = ub0;
      *(uint4*)&Bs[row * KP + (tq << 4) + 8] = ub1;
    }
    __syncthreads();
#pragma unroll
    for (int kk = 0; kk < 2; ++kk) {
      bf16x8 af[4], bfr[4];
#pragma unroll
      for (int i = 0; i < 4; ++i)
        af[i] = *(const bf16x8*)&As[(wy * 64 + i * 16 + l16) * KP + kk * 32 + quad * 8];
#pragma unroll
      for (int j = 0; j < 4; ++j)
        bfr[j] = *(const bf16x8*)&Bs[(wx * 64 + j * 16 + l16) * KP + kk * 32 + quad * 8];
#pragma unroll
      for (int i = 0; i < 4; ++i)
#pragma unroll
        for (int j = 0; j < 4; ++j)
          acc[i][j] = __builtin_amdgcn_mfma_f32_16x16x32_bf16(af[i], bfr[j], acc[i][j], 0, 0, 0);
    }
    __syncthreads();
  }

  float bj[4];
#pragma unroll
  for (int j = 0; j < 4; ++j) bj[j] = bias[wx * 64 + j * 16 + l16];
#pragma unroll
  for (int i = 0; i < 4; ++i) {
#pragma unroll
    for (int r = 0; r < 4; ++r) {
      const int row = n0 + wy * 64 + i * 16 + quad * 4 + r;
      unsigned short* dst =
          (unsigned short*)(mat + (size_t)row * C_ + 4) + c0 + wx * 64 + l16;
#pragma unroll
      for (int j = 0; j < 4; ++j) dst[j * 16] = f2bf(acc[i][j][r] + bj[j]);
    }
  }
}

// ---------------------------------------------------------------------------
// Epilogue v2 (NEW this round): ONE WAVE PER TOKEN — no LDS, no barriers.
// Lane owns 32 consecutive classes (8x uint2 loads in flight); __expf; the
// two softmax halves reduce wave-locally: lanes 0-31 cover hcw [0,1024),
// lanes 32-63 cover roo [1024,2048); 5-step __shfl_xor butterfly inside each
// 32-group + one cross-half __shfl_xor(s,32). In-place logit->prob overwrite
// is same-wave only; fenced with s_waitcnt vmcnt(0) between read and write
// phases (was previously fenced by __syncthreads across waves).
// 8 tokens per 512-thread block -> 2048 blocks (was 16384).
// ---------------------------------------------------------------------------
__global__ __launch_bounds__(512) void epilogue_kernel(
    const int* __restrict__ pY, const int* __restrict__ Yf,
    float* __restrict__ logp, float* __restrict__ mat)
{
  const int w    = threadIdx.x >> 6;
  const int lane = threadIdx.x & 63;
  const int n    = (blockIdx.x << 3) + w;
  float* row = mat + (size_t)n * C_;
  const unsigned short* lg = (const unsigned short*)(row + 4);  // 2048 bf16

  const int py = pY[n];
  const int y  = Yf[n];

  // ---- read phase: 32 consecutive bf16 logits per lane (8B-aligned) ------
  uint2 u[8];
  const unsigned short* base = lg + (lane << 5);
#pragma unroll
  for (int i = 0; i < 8; ++i) u[i] = *(const uint2*)(base + (i << 2));
  const float z = row[0];
  const int ih = min(max(y - 2, 0), FP_ - 1);
  const int ir = min(max(y - 2 - FP_, 0), SP_ - 1);
  const float lh = bf2f(lg[ih]);          // same-address broadcast load
  const float lr = bf2f(lg[FP_ + ir]);

  // ---- exp + wave-local half sums ----------------------------------------
  float e[32];
  float s = 0.f;
#pragma unroll
  for (int i = 0; i < 8; ++i) {
    e[4 * i + 0] = __expf(bf2f((unsigned short)(u[i].x & 0xffffu)));
    e[4 * i + 1] = __expf(bf2f((unsigned short)(u[i].x >> 16)));
    e[4 * i + 2] = __expf(bf2f((unsigned short)(u[i].y & 0xffffu)));
    e[4 * i + 3] = __expf(bf2f((unsigned short)(u[i].y >> 16)));
    s += e[4 * i + 0] + e[4 * i + 1] + e[4 * i + 2] + e[4 * i + 3];
  }
#pragma unroll
  for (int o = 16; o; o >>= 1) s += __shfl_xor(s, o);   // per-32-group sum
  const float so = __shfl_xor(s, 32);                    // other half's sum
  const float Sh = (lane < 32) ? s : so;
  const float Sr = (lane < 32) ? so : s;

  // all reads (incl. lh/lr) must land in regs before in-place writes below
  asm volatile("s_waitcnt vmcnt(0)" ::: "memory");

  // ---- write phase --------------------------------------------------------
  const float sig = 1.f / (1.f + __expf(-z));
  const float ne  = 1.f - sig;
  const float sc = (lane < 32) ? ((py == 1) ? ne / Sh : 0.f)
                               : ((py == 2) ? ne / Sr : 0.f);
  float2* wp = (float2*)(row + 2 + (lane << 5));   // 8B-aligned
#pragma unroll
  for (int k = 0; k < 16; ++k)
    wp[k] = make_float2(e[2 * k] * sc, e[2 * k + 1] * sc);
  if (lane == 0) {
    const float ev = (py == 0) ? sig : 0.f;
    row[0] = ev;
    row[1] = ev;
    const float l1p   = log1pf(__expf(-fabsf(z)));
    const float sp_z  = fmaxf(z, 0.f)  + l1p;
    const float sp_mz = fmaxf(-z, 0.f) + l1p;
    float lp;
    if      (py == 0) lp = -sp_mz;
    else if (py == 1) lp = (lh - __logf(Sh)) - sp_z;
    else if (py == 2) lp = (lr - __logf(Sr)) - sp_z;
    else              lp = 0.f;
    logp[n] = lp;
  }
}

// ---------------------------------------------------------------------------
extern "C" void kernel_launch(void* const* d_in, const int* in_sizes, int n_in,
                              void* d_out, int out_size, void* d_ws, size_t ws_size,
                              hipStream_t stream) {
  const float* X     = (const float*)d_in[0];
  const int*   pY    = (const int*)  d_in[1];
  const int*   Y     = (const int*)  d_in[2];
  const float* W_end = (const float*)d_in[3];
  const float* b_end = (const float*)d_in[4];
  const float* W_hcw = (const float*)d_in[5];
  const float* b_hcw = (const float*)d_in[6];
  const float* W_roo = (const float*)d_in[7];
  const float* b_roo = (const float*)d_in[8];

  float* out  = (float*)d_out;
  float* logp = out;              // [16384]
  float* mat  = out + N_TOK;      // [16384 x 2050], doubles as logit scratch

  const size_t xb_bytes = (size_t)N_TOK * H_ * 2;          // 67,108,864
  const size_t wb_bytes = (size_t)(FP_ + SP_) * H_ * 2;    //  8,388,608
  dim3 g(2048 / BN, N_TOK / BM);  // 16 x 128 blocks

  if (ws_size >= xb_bytes + wb_bytes) {
    unsigned short* Xb = (unsigned short*)d_ws;
    unsigned short* Wb = (unsigned short*)((char*)d_ws + xb_bytes);
    convert_kernel<<<(N_TOK + FP_ + SP_) / 4, 256, 0, stream>>>(
        X, W_hcw, W_roo, W_end, b_end, Xb, Wb, mat);
    gemm_lds_kernel<<<g, 256, 0, stream>>>(Xb, Wb, b_hcw, b_roo, mat);
  } else {
    end_head_kernel<<<N_TOK / 4, 256, 0, stream>>>(X, W_end, b_end, mat);
    logits_gemm_fused<<<g, 256, 0, stream>>>(X, W_hcw, W_roo, b_hcw, b_roo, mat);
  }
  epilogue_kernel<<<N_TOK / 8, 512, 0, stream>>>(pY, Y, logp, mat);
}

// Round 5
// 423.795 us; speedup vs baseline: 1.0642x; 1.0642x over previous
//
#include <hip/hip_runtime.h>
#include <hip/hip_bf16.h>
#include <cstddef>
#include <cstdint>

// Problem constants (fixed by the reference)
#define N_TOK 16384     // B*S = 32*512
#define H_    2048
#define FP_   1024
#define SP_   1024
#define C_    2050      // 2 + FP + SP, prob_all row stride

#define BM 128
#define BN 128
#define BK 64
#define KP 72           // padded stride for the FALLBACK fused kernel only

typedef short bf16x8 __attribute__((ext_vector_type(8)));  // 8 bf16 = 4 VGPRs
typedef float f32x4  __attribute__((ext_vector_type(4)));  // 4 fp32 acc

__device__ __forceinline__ unsigned pack_bf2(float a, float b) {
  __hip_bfloat16 x = __float2bfloat16(a);
  __hip_bfloat16 y = __float2bfloat16(b);
  unsigned short ux, uy;
  __builtin_memcpy(&ux, &x, 2);
  __builtin_memcpy(&uy, &y, 2);
  return (unsigned)ux | ((unsigned)uy << 16);
}

__device__ __forceinline__ unsigned short f2bf(float f) {
  __hip_bfloat16 h = __float2bfloat16(f);
  unsigned short u;
  __builtin_memcpy(&u, &h, 2);
  return u;
}

__device__ __forceinline__ float bf2f(unsigned short u) {
  unsigned v = (unsigned)u << 16;
  float f;
  __builtin_memcpy(&f, &v, 4);
  return f;
}

// ---------------------------------------------------------------------------
// FAST PATH kernel 1: fp32 -> bf16 pre-convert of X (rows 0..16383) and
// W_hcw|W_roo (rows 16384..18431) into d_ws, fusing the end-head dot
// (fp32-exact) into the X pass. One wave per row, 4 rows/block.  (unchanged)
// ---------------------------------------------------------------------------
__global__ __launch_bounds__(256) void convert_kernel(
    const float* __restrict__ X,
    const float* __restrict__ W_hcw, const float* __restrict__ W_roo,
    const float* __restrict__ W_end, const float* __restrict__ b_end,
    unsigned short* __restrict__ Xb, unsigned short* __restrict__ Wb,
    float* __restrict__ mat)
{
  const int wave = threadIdx.x >> 6;
  const int lane = threadIdx.x & 63;
  const int row  = (blockIdx.x << 2) + wave;
  const bool isX = row < N_TOK;
  const float* src;
  unsigned short* dst;
  if (isX) {
    src = X + (size_t)row * H_;
    dst = Xb + (size_t)row * H_;
  } else {
    const int m = row - N_TOK;
    src = (m < FP_) ? (W_hcw + (size_t)m * H_) : (W_roo + (size_t)(m - FP_) * H_);
    dst = Wb + (size_t)m * H_;
  }
  float s = 0.f;
#pragma unroll
  for (int i = 0; i < 8; ++i) {
    const int e = (lane << 2) + (i << 8);      // lane*4 + i*256: coalesced
    float4 v = *(const float4*)(src + e);
    uint2 p;
    p.x = pack_bf2(v.x, v.y);
    p.y = pack_bf2(v.z, v.w);
    *(uint2*)(dst + e) = p;
    if (isX) {                                  // wave-uniform branch
      float4 w = *(const float4*)(W_end + e);
      s += v.x * w.x + v.y * w.y + v.z * w.z + v.w * w.w;
    }
  }
  if (isX) {
#pragma unroll
    for (int o = 32; o; o >>= 1) s += __shfl_xor(s, o);
    if (lane == 0) mat[(size_t)row * C_] = s + b_end[0];
  }
}

// ---------------------------------------------------------------------------
// FAST PATH kernel 2: bf16 MFMA GEMM, async global->LDS staging, XOR-swizzled
// LDS chunk layout (conflict-free). Proven 128^2 2-phase structure (165 us);
// 8-phase/counted-vmcnt schedules measured null-to-worse at this shape
// (rounds 2 & 3). C-tile written as PACKED BF16 logits at float-offset 4.
// ---------------------------------------------------------------------------
__global__ __launch_bounds__(256) void gemm_lds_kernel(
    const unsigned short* __restrict__ Xb, const unsigned short* __restrict__ Wb,
    const float* __restrict__ b_hcw, const float* __restrict__ b_roo,
    float* __restrict__ mat)
{
  __shared__ __align__(16) unsigned short As[BM * BK];   // 16 KB
  __shared__ __align__(16) unsigned short Bs[BN * BK];   // 16 KB

  const int c0 = blockIdx.x * BN;    // class-tile origin; BN divides 1024
  const int n0 = blockIdx.y * BM;    // token-tile origin
  const float* bias = (c0 < FP_) ? (b_hcw + c0) : (b_roo + (c0 - FP_));

  const int t    = threadIdx.x;
  const int wave = t >> 6;
  const int lane = t & 63;
  const int wy   = wave >> 1;
  const int wx   = wave & 1;
  const int quad = lane >> 4;
  const int l16  = lane & 15;

  // staging map: LDS flat byte f = r*4096 + t*16 -> (row = r*32 + t/8,
  // pos = t&7). That slot must hold global chunk pos ^ (row&7).
  const int srow   = t >> 3;                       // 0..31
  const int gchunk = (t & 7) ^ (srow & 7);         // swizzled global chunk
  const unsigned short* gA = Xb + (size_t)(n0 + srow) * H_ + (gchunk << 3);
  const unsigned short* gB = Wb + (size_t)(c0 + srow) * H_ + (gchunk << 3);

  f32x4 acc[4][4];
#pragma unroll
  for (int i = 0; i < 4; ++i)
#pragma unroll
    for (int j = 0; j < 4; ++j)
#pragma unroll
      for (int r = 0; r < 4; ++r) acc[i][j][r] = 0.f;

  for (int k0 = 0; k0 < H_; k0 += BK) {
#pragma unroll
    for (int r = 0; r < 4; ++r) {
      __builtin_amdgcn_global_load_lds(
          (const __attribute__((address_space(1))) unsigned int*)(gA + (size_t)(r * 32) * H_ + k0),
          (__attribute__((address_space(3))) unsigned int*)(&As[(r * 32 + srow) * BK + ((t & 7) << 3)]),
          16, 0, 0);
      __builtin_amdgcn_global_load_lds(
          (const __attribute__((address_space(1))) unsigned int*)(gB + (size_t)(r * 32) * H_ + k0),
          (__attribute__((address_space(3))) unsigned int*)(&Bs[(r * 32 + srow) * BK + ((t & 7) << 3)]),
          16, 0, 0);
    }
    __syncthreads();   // drains vmcnt before barrier (compiler-enforced)

#pragma unroll
    for (int kk = 0; kk < 2; ++kk) {
      bf16x8 af[4], bfr[4];
      const int sw = l16 & 7;                      // row&7 for both A and B rows
#pragma unroll
      for (int i = 0; i < 4; ++i) {
        const int pos = ((kk << 2) + quad) ^ sw;
        af[i] = *(const bf16x8*)&As[(wy * 64 + i * 16 + l16) * BK + (pos << 3)];
      }
#pragma unroll
      for (int j = 0; j < 4; ++j) {
        const int pos = ((kk << 2) + quad) ^ sw;
        bfr[j] = *(const bf16x8*)&Bs[(wx * 64 + j * 16 + l16) * BK + (pos << 3)];
      }
#pragma unroll
      for (int i = 0; i < 4; ++i)
#pragma unroll
        for (int j = 0; j < 4; ++j)
          acc[i][j] = __builtin_amdgcn_mfma_f32_16x16x32_bf16(af[i], bfr[j], acc[i][j], 0, 0, 0);
    }
    __syncthreads();
  }

  // C/D layout: col=lane&15, row=quad*4+reg (m89-verified). Store bf16.
  float bj[4];
#pragma unroll
  for (int j = 0; j < 4; ++j) bj[j] = bias[wx * 64 + j * 16 + l16];
#pragma unroll
  for (int i = 0; i < 4; ++i) {
#pragma unroll
    for (int r = 0; r < 4; ++r) {
      const int row = n0 + wy * 64 + i * 16 + quad * 4 + r;
      unsigned short* dst =
          (unsigned short*)(mat + (size_t)row * C_ + 4) + c0 + wx * 64 + l16;
#pragma unroll
      for (int j = 0; j < 4; ++j) dst[j * 16] = f2bf(acc[i][j][r] + bj[j]);
    }
  }
}

// ---------------------------------------------------------------------------
// FALLBACK kernels (used only if ws_size is too small). Same bf16-logit
// output convention as the fast path so one epilogue serves both.
// ---------------------------------------------------------------------------
__global__ __launch_bounds__(256) void end_head_kernel(
    const float* __restrict__ X, const float* __restrict__ W_end,
    const float* __restrict__ b_end, float* __restrict__ mat)
{
  const int wave = threadIdx.x >> 6;
  const int lane = threadIdx.x & 63;
  const int n = (blockIdx.x << 2) + wave;
  const float* x = X + (size_t)n * H_;
  float s = 0.f;
#pragma unroll
  for (int i = 0; i < 8; ++i) {
    const int e = (lane + (i << 6)) << 2;
    float4 xv = *(const float4*)(x + e);
    float4 wv = *(const float4*)(W_end + e);
    s += xv.x * wv.x + xv.y * wv.y + xv.z * wv.z + xv.w * wv.w;
  }
#pragma unroll
  for (int o = 32; o; o >>= 1) s += __shfl_xor(s, o);
  if (lane == 0) mat[(size_t)n * C_] = s + b_end[0];
}

__global__ __launch_bounds__(256) void logits_gemm_fused(
    const float* __restrict__ X,
    const float* __restrict__ W_hcw, const float* __restrict__ W_roo,
    const float* __restrict__ b_hcw, const float* __restrict__ b_roo,
    float* __restrict__ mat)
{
  __shared__ __align__(16) unsigned short As[BM * KP];
  __shared__ __align__(16) unsigned short Bs[BN * KP];

  const int c0 = blockIdx.x * BN;
  const int n0 = blockIdx.y * BM;
  const float* Wbase = (c0 < FP_) ? (W_hcw + (size_t)c0 * H_)
                                  : (W_roo + (size_t)(c0 - FP_) * H_);
  const float* bias  = (c0 < FP_) ? (b_hcw + c0) : (b_roo + (c0 - FP_));

  const int t    = threadIdx.x;
  const int wave = t >> 6;
  const int lane = t & 63;
  const int wy   = wave >> 1;
  const int wx   = wave & 1;
  const int quad = lane >> 4;
  const int l16  = lane & 15;
  const int tq = t & 3;
  const int tr = t >> 2;

  f32x4 acc[4][4];
#pragma unroll
  for (int i = 0; i < 4; ++i)
#pragma unroll
    for (int j = 0; j < 4; ++j)
#pragma unroll
      for (int r = 0; r < 4; ++r) acc[i][j][r] = 0.f;

  for (int k0 = 0; k0 < H_; k0 += BK) {
#pragma unroll
    for (int p = 0; p < 2; ++p) {
      const int row = tr + (p << 6);
      const float4* xs = (const float4*)(X + (size_t)(n0 + row) * H_ + k0 + (tq << 4));
      const float4* ws = (const float4*)(Wbase + (size_t)row * H_ + k0 + (tq << 4));
      float4 x0 = xs[0], x1 = xs[1], x2 = xs[2], x3 = xs[3];
      float4 w0 = ws[0], w1 = ws[1], w2 = ws[2], w3 = ws[3];
      uint4 ua0 = {pack_bf2(x0.x, x0.y), pack_bf2(x0.z, x0.w),
                   pack_bf2(x1.x, x1.y), pack_bf2(x1.z, x1.w)};
      uint4 ua1 = {pack_bf2(x2.x, x2.y), pack_bf2(x2.z, x2.w),
                   pack_bf2(x3.x, x3.y), pack_bf2(x3.z, x3.w)};
      uint4 ub0 = {pack_bf2(w0.x, w0.y), pack_bf2(w0.z, w0.w),
                   pack_bf2(w1.x, w1.y), pack_bf2(w1.z, w1.w)};
      uint4 ub1 = {pack_bf2(w2.x, w2.y), pack_bf2(w2.z, w2.w),
                   pack_bf2(w3.x, w3.y), pack_bf2(w3.z, w3.w)};
      *(uint4*)&As[row * KP + (tq << 4)]     = ua0;
      *(uint4*)&As[row * KP + (tq << 4) + 8] = ua1;
      *(uint4*)&Bs[row * KP + (tq << 4)]     = ub0;
      *(uint4*)&Bs[row * KP + (tq << 4) + 8] = ub1;
    }
    __syncthreads();
#pragma unroll
    for (int kk = 0; kk < 2; ++kk) {
      bf16x8 af[4], bfr[4];
#pragma unroll
      for (int i = 0; i < 4; ++i)
        af[i] = *(const bf16x8*)&As[(wy * 64 + i * 16 + l16) * KP + kk * 32 + quad * 8];
#pragma unroll
      for (int j = 0; j < 4; ++j)
        bfr[j] = *(const bf16x8*)&Bs[(wx * 64 + j * 16 + l16) * KP + kk * 32 + quad * 8];
#pragma unroll
      for (int i = 0; i < 4; ++i)
#pragma unroll
        for (int j = 0; j < 4; ++j)
          acc[i][j] = __builtin_amdgcn_mfma_f32_16x16x32_bf16(af[i], bfr[j], acc[i][j], 0, 0, 0);
    }
    __syncthreads();
  }

  float bj[4];
#pragma unroll
  for (int j = 0; j < 4; ++j) bj[j] = bias[wx * 64 + j * 16 + l16];
#pragma unroll
  for (int i = 0; i < 4; ++i) {
#pragma unroll
    for (int r = 0; r < 4; ++r) {
      const int row = n0 + wy * 64 + i * 16 + quad * 4 + r;
      unsigned short* dst =
          (unsigned short*)(mat + (size_t)row * C_ + 4) + c0 + wx * 64 + l16;
#pragma unroll
      for (int j = 0; j < 4; ++j) dst[j * 16] = f2bf(acc[i][j][r] + bj[j]);
    }
  }
}

// ---------------------------------------------------------------------------
// Epilogue v3 (NEW this round): one wave per token + INTERLEAVED ownership.
// At iteration i, lane l owns classes i*256 + l*4 .. +3:
//   reads:  uint2 at lg + i*512B + lane*8B  -> contiguous 512B / instruction
//   writes: 2x float2 at row+2+i*1024B+lane*16B -> contiguous 1KB / iter
// (v1's coalescing or better, v2's zero-barrier/zero-LDS structure; R4
// showed v2's stride-64B/128B accesses cost ~16 us vs v1.)
// Softmax halves land on iteration groups (i<4 = hcw, i>=4 = roo): two
// 6-step full-wave __shfl_xor butterflies. 8 tokens per 512-thread block.
// In-place logit->prob overwrite is same-wave only; fenced with
// s_waitcnt vmcnt(0) between read and write phases.
// ---------------------------------------------------------------------------
__global__ __launch_bounds__(512) void epilogue_kernel(
    const int* __restrict__ pY, const int* __restrict__ Yf,
    float* __restrict__ logp, float* __restrict__ mat)
{
  const int w    = threadIdx.x >> 6;
  const int lane = threadIdx.x & 63;
  const int n    = (blockIdx.x << 3) + w;
  float* row = mat + (size_t)n * C_;
  const unsigned short* lg = (const unsigned short*)(row + 4);  // 2048 bf16

  const int py = pY[n];
  const int y  = Yf[n];

  // ---- read phase: iteration i covers classes [i*256, i*256+256) ---------
  uint2 u[8];
#pragma unroll
  for (int i = 0; i < 8; ++i)
    u[i] = *(const uint2*)(lg + (i << 8) + (lane << 2));   // 8B aligned
  const float z = row[0];
  const int ih = min(max(y - 2, 0), FP_ - 1);
  const int ir = min(max(y - 2 - FP_, 0), SP_ - 1);
  const float lh = bf2f(lg[ih]);          // same-address broadcast load
  const float lr = bf2f(lg[FP_ + ir]);

  // ---- exp + two full-wave butterfly sums (i<4 = hcw, i>=4 = roo) --------
  float e[32];
  float sh = 0.f, sr = 0.f;
#pragma unroll
  for (int i = 0; i < 8; ++i) {
    const float e0 = __expf(bf2f((unsigned short)(u[i].x & 0xffffu)));
    const float e1 = __expf(bf2f((unsigned short)(u[i].x >> 16)));
    const float e2 = __expf(bf2f((unsigned short)(u[i].y & 0xffffu)));
    const float e3 = __expf(bf2f((unsigned short)(u[i].y >> 16)));
    e[4 * i + 0] = e0; e[4 * i + 1] = e1; e[4 * i + 2] = e2; e[4 * i + 3] = e3;
    if (i < 4) sh += e0 + e1 + e2 + e3;
    else       sr += e0 + e1 + e2 + e3;
  }
#pragma unroll
  for (int o = 32; o; o >>= 1) sh += __shfl_xor(sh, o);
#pragma unroll
  for (int o = 32; o; o >>= 1) sr += __shfl_xor(sr, o);
  const float Sh = sh, Sr = sr;

  // all reads (incl. lh/lr/z) must be in regs before in-place writes below
  asm volatile("s_waitcnt vmcnt(0)" ::: "memory");

  // ---- write phase --------------------------------------------------------
  const float sig = 1.f / (1.f + __expf(-z));
  const float ne  = 1.f - sig;
  const float sch = (py == 1) ? ne / Sh : 0.f;
  const float scr = (py == 2) ? ne / Sr : 0.f;
#pragma unroll
  for (int i = 0; i < 8; ++i) {
    const float sc = (i < 4) ? sch : scr;
    float2* wp = (float2*)(row + 2 + (i << 8) + (lane << 2));  // 8B aligned
    wp[0] = make_float2(e[4 * i + 0] * sc, e[4 * i + 1] * sc);
    wp[1] = make_float2(e[4 * i + 2] * sc, e[4 * i + 3] * sc);
  }
  if (lane == 0) {
    const float ev = (py == 0) ? sig : 0.f;
    row[0] = ev;
    row[1] = ev;
    const float l1p   = log1pf(__expf(-fabsf(z)));
    const float sp_z  = fmaxf(z, 0.f)  + l1p;
    const float sp_mz = fmaxf(-z, 0.f) + l1p;
    float lp;
    if      (py == 0) lp = -sp_mz;
    else if (py == 1) lp = (lh - __logf(Sh)) - sp_z;
    else if (py == 2) lp = (lr - __logf(Sr)) - sp_z;
    else              lp = 0.f;
    logp[n] = lp;
  }
}

// ---------------------------------------------------------------------------
extern "C" void kernel_launch(void* const* d_in, const int* in_sizes, int n_in,
                              void* d_out, int out_size, void* d_ws, size_t ws_size,
                              hipStream_t stream) {
  const float* X     = (const float*)d_in[0];
  const int*   pY    = (const int*)  d_in[1];
  const int*   Y     = (const int*)  d_in[2];
  const float* W_end = (const float*)d_in[3];
  const float* b_end = (const float*)d_in[4];
  const float* W_hcw = (const float*)d_in[5];
  const float* b_hcw = (const float*)d_in[6];
  const float* W_roo = (const float*)d_in[7];
  const float* b_roo = (const float*)d_in[8];

  float* out  = (float*)d_out;
  float* logp = out;              // [16384]
  float* mat  = out + N_TOK;      // [16384 x 2050], doubles as logit scratch

  const size_t xb_bytes = (size_t)N_TOK * H_ * 2;          // 67,108,864
  const size_t wb_bytes = (size_t)(FP_ + SP_) * H_ * 2;    //  8,388,608
  dim3 g(2048 / BN, N_TOK / BM);  // 16 x 128 blocks

  if (ws_size >= xb_bytes + wb_bytes) {
    unsigned short* Xb = (unsigned short*)d_ws;
    unsigned short* Wb = (unsigned short*)((char*)d_ws + xb_bytes);
    convert_kernel<<<(N_TOK + FP_ + SP_) / 4, 256, 0, stream>>>(
        X, W_hcw, W_roo, W_end, b_end, Xb, Wb, mat);
    gemm_lds_kernel<<<g, 256, 0, stream>>>(Xb, Wb, b_hcw, b_roo, mat);
  } else {
    end_head_kernel<<<N_TOK / 4, 256, 0, stream>>>(X, W_end, b_end, mat);
    logits_gemm_fused<<<g, 256, 0, stream>>>(X, W_hcw, W_roo, b_hcw, b_roo, mat);
  }
  epilogue_kernel<<<N_TOK / 8, 512, 0, stream>>>(pY, Y, logp, mat);
}

// Round 6
// 417.241 us; speedup vs baseline: 1.0809x; 1.0157x over previous
//
#include <hip/hip_runtime.h>
#include <hip/hip_bf16.h>
#include <cstddef>
#include <cstdint>

// Problem constants (fixed by the reference)
#define N_TOK 16384     // B*S = 32*512
#define H_    2048
#define FP_   1024
#define SP_   1024
#define C_    2050      // 2 + FP + SP, prob_all row stride

#define BM 128
#define BN 128
#define BK 64
#define KP 72           // padded stride for the FALLBACK fused kernel only

typedef short bf16x8 __attribute__((ext_vector_type(8)));  // 8 bf16 = 4 VGPRs
typedef float f32x4  __attribute__((ext_vector_type(4)));  // 4 fp32 acc
typedef float f4     __attribute__((ext_vector_type(4)));  // for nt load
typedef float f2     __attribute__((ext_vector_type(2)));  // for nt store

__device__ __forceinline__ unsigned pack_bf2(float a, float b) {
  __hip_bfloat16 x = __float2bfloat16(a);
  __hip_bfloat16 y = __float2bfloat16(b);
  unsigned short ux, uy;
  __builtin_memcpy(&ux, &x, 2);
  __builtin_memcpy(&uy, &y, 2);
  return (unsigned)ux | ((unsigned)uy << 16);
}

__device__ __forceinline__ unsigned short f2bf(float f) {
  __hip_bfloat16 h = __float2bfloat16(f);
  unsigned short u;
  __builtin_memcpy(&u, &h, 2);
  return u;
}

__device__ __forceinline__ float bf2f(unsigned short u) {
  unsigned v = (unsigned)u << 16;
  float f;
  __builtin_memcpy(&f, &v, 4);
  return f;
}

// ---------------------------------------------------------------------------
// FAST PATH kernel 1: fp32 -> bf16 pre-convert of X (rows 0..16383) and
// W_hcw|W_roo (rows 16384..18431) into d_ws, fusing the end-head dot into
// the X pass. NEW this round: X / W fp32 source reads are NON-TEMPORAL
// (read-once, 160 MB) so they stop evicting Xb/W/mat-logits from L3.
// ---------------------------------------------------------------------------
__global__ __launch_bounds__(256) void convert_kernel(
    const float* __restrict__ X,
    const float* __restrict__ W_hcw, const float* __restrict__ W_roo,
    const float* __restrict__ W_end, const float* __restrict__ b_end,
    unsigned short* __restrict__ Xb, unsigned short* __restrict__ Wb,
    float* __restrict__ mat)
{
  const int wave = threadIdx.x >> 6;
  const int lane = threadIdx.x & 63;
  const int row  = (blockIdx.x << 2) + wave;
  const bool isX = row < N_TOK;
  const float* src;
  unsigned short* dst;
  if (isX) {
    src = X + (size_t)row * H_;
    dst = Xb + (size_t)row * H_;
  } else {
    const int m = row - N_TOK;
    src = (m < FP_) ? (W_hcw + (size_t)m * H_) : (W_roo + (size_t)(m - FP_) * H_);
    dst = Wb + (size_t)m * H_;
  }
  float s = 0.f;
#pragma unroll
  for (int i = 0; i < 8; ++i) {
    const int e = (lane << 2) + (i << 8);      // lane*4 + i*256: coalesced
    f4 v = __builtin_nontemporal_load((const f4*)(src + e));
    uint2 p;
    p.x = pack_bf2(v[0], v[1]);
    p.y = pack_bf2(v[2], v[3]);
    *(uint2*)(dst + e) = p;                     // Xb/Wb re-read by GEMM: cached
    if (isX) {                                  // wave-uniform branch
      float4 w = *(const float4*)(W_end + e);   // 8 KB, reused: cached
      s += v[0] * w.x + v[1] * w.y + v[2] * w.z + v[3] * w.w;
    }
  }
  if (isX) {
#pragma unroll
    for (int o = 32; o; o >>= 1) s += __shfl_xor(s, o);
    if (lane == 0) mat[(size_t)row * C_] = s + b_end[0];
  }
}

// ---------------------------------------------------------------------------
// FAST PATH kernel 2: bf16 MFMA GEMM, async global->LDS staging, XOR-swizzled
// LDS chunk layout (conflict-free). Proven 128^2 2-phase structure;
// 8-phase/counted-vmcnt schedules measured null at this shape (r2, r3).
// NEW this round: XCD-PINNED 1D block swizzle — each XCD owns 2 col-tiles
// (W working set 1 MB -> L2-resident across all 128 row-panels) and all
// XCDs walk row-panels co-temporally (Xb served from L3 once). Bijective:
// bid -> col=(bid&7)*2+((bid>>3)&1), rowp=bid>>4. Inner loop unchanged.
// ---------------------------------------------------------------------------
__global__ __launch_bounds__(256) void gemm_lds_kernel(
    const unsigned short* __restrict__ Xb, const unsigned short* __restrict__ Wb,
    const float* __restrict__ b_hcw, const float* __restrict__ b_roo,
    float* __restrict__ mat)
{
  __shared__ __align__(16) unsigned short As[BM * BK];   // 16 KB
  __shared__ __align__(16) unsigned short Bs[BN * BK];   // 16 KB

  const int bid = blockIdx.x;              // 0..2047
  const int xcd = bid & 7;                 // dispatch round-robins XCDs
  const int loc = bid >> 3;                // 0..255 within XCD
  const int c0 = (((xcd << 1) | (loc & 1))) * BN;   // col-tile 0..15
  const int n0 = (loc >> 1) * BM;                    // row-panel 0..127
  const float* bias = (c0 < FP_) ? (b_hcw + c0) : (b_roo + (c0 - FP_));

  const int t    = threadIdx.x;
  const int wave = t >> 6;
  const int lane = t & 63;
  const int wy   = wave >> 1;
  const int wx   = wave & 1;
  const int quad = lane >> 4;
  const int l16  = lane & 15;

  // staging map: LDS flat byte f = r*4096 + t*16 -> (row = r*32 + t/8,
  // pos = t&7). That slot must hold global chunk pos ^ (row&7).
  const int srow   = t >> 3;                       // 0..31
  const int gchunk = (t & 7) ^ (srow & 7);         // swizzled global chunk
  const unsigned short* gA = Xb + (size_t)(n0 + srow) * H_ + (gchunk << 3);
  const unsigned short* gB = Wb + (size_t)(c0 + srow) * H_ + (gchunk << 3);

  f32x4 acc[4][4];
#pragma unroll
  for (int i = 0; i < 4; ++i)
#pragma unroll
    for (int j = 0; j < 4; ++j)
#pragma unroll
      for (int r = 0; r < 4; ++r) acc[i][j][r] = 0.f;

  for (int k0 = 0; k0 < H_; k0 += BK) {
#pragma unroll
    for (int r = 0; r < 4; ++r) {
      __builtin_amdgcn_global_load_lds(
          (const __attribute__((address_space(1))) unsigned int*)(gA + (size_t)(r * 32) * H_ + k0),
          (__attribute__((address_space(3))) unsigned int*)(&As[(r * 32 + srow) * BK + ((t & 7) << 3)]),
          16, 0, 0);
      __builtin_amdgcn_global_load_lds(
          (const __attribute__((address_space(1))) unsigned int*)(gB + (size_t)(r * 32) * H_ + k0),
          (__attribute__((address_space(3))) unsigned int*)(&Bs[(r * 32 + srow) * BK + ((t & 7) << 3)]),
          16, 0, 0);
    }
    __syncthreads();   // drains vmcnt before barrier (compiler-enforced)

#pragma unroll
    for (int kk = 0; kk < 2; ++kk) {
      bf16x8 af[4], bfr[4];
      const int sw = l16 & 7;                      // row&7 for both A and B rows
#pragma unroll
      for (int i = 0; i < 4; ++i) {
        const int pos = ((kk << 2) + quad) ^ sw;
        af[i] = *(const bf16x8*)&As[(wy * 64 + i * 16 + l16) * BK + (pos << 3)];
      }
#pragma unroll
      for (int j = 0; j < 4; ++j) {
        const int pos = ((kk << 2) + quad) ^ sw;
        bfr[j] = *(const bf16x8*)&Bs[(wx * 64 + j * 16 + l16) * BK + (pos << 3)];
      }
#pragma unroll
      for (int i = 0; i < 4; ++i)
#pragma unroll
        for (int j = 0; j < 4; ++j)
          acc[i][j] = __builtin_amdgcn_mfma_f32_16x16x32_bf16(af[i], bfr[j], acc[i][j], 0, 0, 0);
    }
    __syncthreads();
  }

  // C/D layout: col=lane&15, row=quad*4+reg (m89-verified). Store bf16.
  float bj[4];
#pragma unroll
  for (int j = 0; j < 4; ++j) bj[j] = bias[wx * 64 + j * 16 + l16];
#pragma unroll
  for (int i = 0; i < 4; ++i) {
#pragma unroll
    for (int r = 0; r < 4; ++r) {
      const int row = n0 + wy * 64 + i * 16 + quad * 4 + r;
      unsigned short* dst =
          (unsigned short*)(mat + (size_t)row * C_ + 4) + c0 + wx * 64 + l16;
#pragma unroll
      for (int j = 0; j < 4; ++j) dst[j * 16] = f2bf(acc[i][j][r] + bj[j]);
    }
  }
}

// ---------------------------------------------------------------------------
// FALLBACK kernels (used only if ws_size is too small). Same bf16-logit
// output convention as the fast path so one epilogue serves both.
// ---------------------------------------------------------------------------
__global__ __launch_bounds__(256) void end_head_kernel(
    const float* __restrict__ X, const float* __restrict__ W_end,
    const float* __restrict__ b_end, float* __restrict__ mat)
{
  const int wave = threadIdx.x >> 6;
  const int lane = threadIdx.x & 63;
  const int n = (blockIdx.x << 2) + wave;
  const float* x = X + (size_t)n * H_;
  float s = 0.f;
#pragma unroll
  for (int i = 0; i < 8; ++i) {
    const int e = (lane + (i << 6)) << 2;
    float4 xv = *(const float4*)(x + e);
    float4 wv = *(const float4*)(W_end + e);
    s += xv.x * wv.x + xv.y * wv.y + xv.z * wv.z + xv.w * wv.w;
  }
#pragma unroll
  for (int o = 32; o; o >>= 1) s += __shfl_xor(s, o);
  if (lane == 0) mat[(size_t)n * C_] = s + b_end[0];
}

__global__ __launch_bounds__(256) void logits_gemm_fused(
    const float* __restrict__ X,
    const float* __restrict__ W_hcw, const float* __restrict__ W_roo,
    const float* __restrict__ b_hcw, const float* __restrict__ b_roo,
    float* __restrict__ mat)
{
  __shared__ __align__(16) unsigned short As[BM * KP];
  __shared__ __align__(16) unsigned short Bs[BN * KP];

  const int c0 = blockIdx.x * BN;
  const int n0 = blockIdx.y * BM;
  const float* Wbase = (c0 < FP_) ? (W_hcw + (size_t)c0 * H_)
                                  : (W_roo + (size_t)(c0 - FP_) * H_);
  const float* bias  = (c0 < FP_) ? (b_hcw + c0) : (b_roo + (c0 - FP_));

  const int t    = threadIdx.x;
  const int wave = t >> 6;
  const int lane = t & 63;
  const int wy   = wave >> 1;
  const int wx   = wave & 1;
  const int quad = lane >> 4;
  const int l16  = lane & 15;
  const int tq = t & 3;
  const int tr = t >> 2;

  f32x4 acc[4][4];
#pragma unroll
  for (int i = 0; i < 4; ++i)
#pragma unroll
    for (int j = 0; j < 4; ++j)
#pragma unroll
      for (int r = 0; r < 4; ++r) acc[i][j][r] = 0.f;

  for (int k0 = 0; k0 < H_; k0 += BK) {
#pragma unroll
    for (int p = 0; p < 2; ++p) {
      const int row = tr + (p << 6);
      const float4* xs = (const float4*)(X + (size_t)(n0 + row) * H_ + k0 + (tq << 4));
      const float4* ws = (const float4*)(Wbase + (size_t)row * H_ + k0 + (tq << 4));
      float4 x0 = xs[0], x1 = xs[1], x2 = xs[2], x3 = xs[3];
      float4 w0 = ws[0], w1 = ws[1], w2 = ws[2], w3 = ws[3];
      uint4 ua0 = {pack_bf2(x0.x, x0.y), pack_bf2(x0.z, x0.w),
                   pack_bf2(x1.x, x1.y), pack_bf2(x1.z, x1.w)};
      uint4 ua1 = {pack_bf2(x2.x, x2.y), pack_bf2(x2.z, x2.w),
                   pack_bf2(x3.x, x3.y), pack_bf2(x3.z, x3.w)};
      uint4 ub0 = {pack_bf2(w0.x, w0.y), pack_bf2(w0.z, w0.w),
                   pack_bf2(w1.x, w1.y), pack_bf2(w1.z, w1.w)};
      uint4 ub1 = {pack_bf2(w2.x, w2.y), pack_bf2(w2.z, w2.w),
                   pack_bf2(w3.x, w3.y), pack_bf2(w3.z, w3.w)};
      *(uint4*)&As[row * KP + (tq << 4)]     = ua0;
      *(uint4*)&As[row * KP + (tq << 4) + 8] = ua1;
      *(uint4*)&Bs[row * KP + (tq << 4)]     = ub0;
      *(uint4*)&Bs[row * KP + (tq << 4) + 8] = ub1;
    }
    __syncthreads();
#pragma unroll
    for (int kk = 0; kk < 2; ++kk) {
      bf16x8 af[4], bfr[4];
#pragma unroll
      for (int i = 0; i < 4; ++i)
        af[i] = *(const bf16x8*)&As[(wy * 64 + i * 16 + l16) * KP + kk * 32 + quad * 8];
#pragma unroll
      for (int j = 0; j < 4; ++j)
        bfr[j] = *(const bf16x8*)&Bs[(wx * 64 + j * 16 + l16) * KP + kk * 32 + quad * 8];
#pragma unroll
      for (int i = 0; i < 4; ++i)
#pragma unroll
        for (int j = 0; j < 4; ++j)
          acc[i][j] = __builtin_amdgcn_mfma_f32_16x16x32_bf16(af[i], bfr[j], acc[i][j], 0, 0, 0);
    }
    __syncthreads();
  }

  float bj[4];
#pragma unroll
  for (int j = 0; j < 4; ++j) bj[j] = bias[wx * 64 + j * 16 + l16];
#pragma unroll
  for (int i = 0; i < 4; ++i) {
#pragma unroll
    for (int r = 0; r < 4; ++r) {
      const int row = n0 + wy * 64 + i * 16 + quad * 4 + r;
      unsigned short* dst =
          (unsigned short*)(mat + (size_t)row * C_ + 4) + c0 + wx * 64 + l16;
#pragma unroll
      for (int j = 0; j < 4; ++j) dst[j * 16] = f2bf(acc[i][j][r] + bj[j]);
    }
  }
}

// ---------------------------------------------------------------------------
// Epilogue v3 + NT stores: one wave per token, interleaved ownership
// (iteration i, lane l owns classes i*256 + l*4 .. +3 -> fully-contiguous
// 512B reads / 1KB writes per instruction group), zero barriers/LDS.
// NEW this round: prob writes (134 MB, never re-read on device) are
// NON-TEMPORAL so they stop thrashing L3.
// ---------------------------------------------------------------------------
__global__ __launch_bounds__(512) void epilogue_kernel(
    const int* __restrict__ pY, const int* __restrict__ Yf,
    float* __restrict__ logp, float* __restrict__ mat)
{
  const int w    = threadIdx.x >> 6;
  const int lane = threadIdx.x & 63;
  const int n    = (blockIdx.x << 3) + w;
  float* row = mat + (size_t)n * C_;
  const unsigned short* lg = (const unsigned short*)(row + 4);  // 2048 bf16

  const int py = pY[n];
  const int y  = Yf[n];

  // ---- read phase: iteration i covers classes [i*256, i*256+256) ---------
  uint2 u[8];
#pragma unroll
  for (int i = 0; i < 8; ++i)
    u[i] = *(const uint2*)(lg + (i << 8) + (lane << 2));   // 8B aligned
  const float z = row[0];
  const int ih = min(max(y - 2, 0), FP_ - 1);
  const int ir = min(max(y - 2 - FP_, 0), SP_ - 1);
  const float lh = bf2f(lg[ih]);          // same-address broadcast load
  const float lr = bf2f(lg[FP_ + ir]);

  // ---- exp + two full-wave butterfly sums (i<4 = hcw, i>=4 = roo) --------
  float e[32];
  float sh = 0.f, sr = 0.f;
#pragma unroll
  for (int i = 0; i < 8; ++i) {
    const float e0 = __expf(bf2f((unsigned short)(u[i].x & 0xffffu)));
    const float e1 = __expf(bf2f((unsigned short)(u[i].x >> 16)));
    const float e2 = __expf(bf2f((unsigned short)(u[i].y & 0xffffu)));
    const float e3 = __expf(bf2f((unsigned short)(u[i].y >> 16)));
    e[4 * i + 0] = e0; e[4 * i + 1] = e1; e[4 * i + 2] = e2; e[4 * i + 3] = e3;
    if (i < 4) sh += e0 + e1 + e2 + e3;
    else       sr += e0 + e1 + e2 + e3;
  }
#pragma unroll
  for (int o = 32; o; o >>= 1) sh += __shfl_xor(sh, o);
#pragma unroll
  for (int o = 32; o; o >>= 1) sr += __shfl_xor(sr, o);
  const float Sh = sh, Sr = sr;

  // all reads (incl. lh/lr/z) must be in regs before in-place writes below
  asm volatile("s_waitcnt vmcnt(0)" ::: "memory");

  // ---- write phase (non-temporal: probs never re-read on device) ---------
  const float sig = 1.f / (1.f + __expf(-z));
  const float ne  = 1.f - sig;
  const float sch = (py == 1) ? ne / Sh : 0.f;
  const float scr = (py == 2) ? ne / Sr : 0.f;
#pragma unroll
  for (int i = 0; i < 8; ++i) {
    const float sc = (i < 4) ? sch : scr;
    f2* wp = (f2*)(row + 2 + (i << 8) + (lane << 2));  // 8B aligned
    f2 v0 = {e[4 * i + 0] * sc, e[4 * i + 1] * sc};
    f2 v1 = {e[4 * i + 2] * sc, e[4 * i + 3] * sc};
    __builtin_nontemporal_store(v0, wp);
    __builtin_nontemporal_store(v1, wp + 1);
  }
  if (lane == 0) {
    const float ev = (py == 0) ? sig : 0.f;
    row[0] = ev;
    row[1] = ev;
    const float l1p   = log1pf(__expf(-fabsf(z)));
    const float sp_z  = fmaxf(z, 0.f)  + l1p;
    const float sp_mz = fmaxf(-z, 0.f) + l1p;
    float lp;
    if      (py == 0) lp = -sp_mz;
    else if (py == 1) lp = (lh - __logf(Sh)) - sp_z;
    else if (py == 2) lp = (lr - __logf(Sr)) - sp_z;
    else              lp = 0.f;
    logp[n] = lp;
  }
}

// ---------------------------------------------------------------------------
extern "C" void kernel_launch(void* const* d_in, const int* in_sizes, int n_in,
                              void* d_out, int out_size, void* d_ws, size_t ws_size,
                              hipStream_t stream) {
  const float* X     = (const float*)d_in[0];
  const int*   pY    = (const int*)  d_in[1];
  const int*   Y     = (const int*)  d_in[2];
  const float* W_end = (const float*)d_in[3];
  const float* b_end = (const float*)d_in[4];
  const float* W_hcw = (const float*)d_in[5];
  const float* b_hcw = (const float*)d_in[6];
  const float* W_roo = (const float*)d_in[7];
  const float* b_roo = (const float*)d_in[8];

  float* out  = (float*)d_out;
  float* logp = out;              // [16384]
  float* mat  = out + N_TOK;      // [16384 x 2050], doubles as logit scratch

  const size_t xb_bytes = (size_t)N_TOK * H_ * 2;          // 67,108,864
  const size_t wb_bytes = (size_t)(FP_ + SP_) * H_ * 2;    //  8,388,608

  if (ws_size >= xb_bytes + wb_bytes) {
    unsigned short* Xb = (unsigned short*)d_ws;
    unsigned short* Wb = (unsigned short*)((char*)d_ws + xb_bytes);
    convert_kernel<<<(N_TOK + FP_ + SP_) / 4, 256, 0, stream>>>(
        X, W_hcw, W_roo, W_end, b_end, Xb, Wb, mat);
    gemm_lds_kernel<<<2048, 256, 0, stream>>>(Xb, Wb, b_hcw, b_roo, mat);
  } else {
    dim3 g(2048 / BN, N_TOK / BM);  // 16 x 128 blocks
    end_head_kernel<<<N_TOK / 4, 256, 0, stream>>>(X, W_end, b_end, mat);
    logits_gemm_fused<<<g, 256, 0, stream>>>(X, W_hcw, W_roo, b_hcw, b_roo, mat);
  }
  epilogue_kernel<<<N_TOK / 8, 512, 0, stream>>>(pY, Y, logp, mat);
}